// Round 1
// 2954.123 us; speedup vs baseline: 1.8336x; 1.8336x over previous
//
#include <hip/hip_runtime.h>
#include <math.h>

#define N_NODES   50000
#define N_EDGES   400000
#define NUM_INPUT 3703
#define NUM_DIM   256
#define NUM_OUT   6

#define KPAD   3712      // 116 * 32, zero-padded K for W1 split arrays
#define KTILES 116

typedef __attribute__((ext_vector_type(8))) short short8;
typedef __attribute__((ext_vector_type(4))) float f32x4;

// fp32 -> bf16 (round-to-nearest-even), manual so behavior is explicit
static __device__ __forceinline__ unsigned short f2bf(float f) {
    unsigned u = __float_as_uint(f);
    u += 0x7fffu + ((u >> 16) & 1u);
    return (unsigned short)(u >> 16);
}
static __device__ __forceinline__ float bf2f(unsigned short h) {
    return __uint_as_float(((unsigned)h) << 16);
}

// ---------------------------------------------------------------------------
// w1_split: W1[k][col] -> W1t_hi/lo[col][k] (bf16, transposed, K zero-padded
// to 3712). Runs once per launch; makes gemm1's B-staging a raw
// global_load_lds with no per-tile conversion VALU (741M conversions saved).
// ---------------------------------------------------------------------------
__global__ __launch_bounds__(256) void w1_split_kernel(
    const float* __restrict__ W1,
    unsigned short* __restrict__ Wh, unsigned short* __restrict__ Wl)
{
    int idx = blockIdx.x * 256 + threadIdx.x;      // [0, 256*3712)
    if (idx >= NUM_DIM * KPAD) return;
    int col = idx / KPAD;
    int k   = idx - col * KPAD;
    float v = (k < NUM_INPUT) ? W1[(size_t)k * NUM_DIM + col] : 0.f;
    unsigned short h = f2bf(v);
    Wh[idx] = h;
    Wl[idx] = f2bf(v - bf2f(h));
}

// ---------------------------------------------------------------------------
// GEMM1 (MFMA, split-bf16): support = x @ W1.  M=50000, K=3703, N=256.
// Block: 64 rows x 256 cols, 256 threads = 4 waves; wave w owns cols w*64..+63
// as 4x4 fragments of mfma_f32_16x16x32_bf16 (fp32 accum).
// support = Ah*Bh + Ah*Bl + Al*Bh  (Al*Bl dropped, ~2^-18 relative).
// A (x) is split in-kernel during staging; B comes pre-split/pre-transposed.
// LDS tiles use 64B row stride -> fragment ds_read_b128 spread evenly over
// all 8 16B bank slots (conflict-minimal). B staged via global_load_lds
// (dest = t*16: wave-uniform base + lane*16).
// ---------------------------------------------------------------------------
__global__ __launch_bounds__(256) void gemm1_kernel(
    const float* __restrict__ x,
    const unsigned short* __restrict__ Wh, const unsigned short* __restrict__ Wl,
    float* __restrict__ support)
{
    __shared__ unsigned short Ah[64][32];    // 4 KB  [row][k]
    __shared__ unsigned short Al[64][32];    // 4 KB
    __shared__ unsigned short Bh[256][32];   // 16 KB [col][k]
    __shared__ unsigned short Bl[256][32];   // 16 KB

    const int t    = threadIdx.x;
    const int lane = t & 63;
    const int wv   = t >> 6;                 // wave 0..3 -> col block
    const int m0   = blockIdx.x * 64;

    const int arow = t >> 2;                 // staging: row 0..63
    const int akc  = t & 3;                  // staging: k-chunk 0..3 (8 elems)
    const int fr   = lane & 15;              // frag row (A) / col (B,D)
    const int fg   = lane >> 4;              // frag k-group 0..3

    const int gr   = m0 + arow;
    const bool rok = (gr < N_NODES);
    const float* xrow = x + (size_t)gr * NUM_INPUT + akc * 8;

    // LDS staging destinations: linear t*16 within each tile
    char* ah_dst = (char*)&Ah[0][0] + t * 16;
    char* al_dst = (char*)&Al[0][0] + t * 16;
    char* bh_dst = (char*)&Bh[0][0] + t * 16;
    char* bl_dst = (char*)&Bl[0][0] + t * 16;
    const int bcol0 = t >> 2;                // B staging col (+64 per round)

    f32x4 acc[4][4];
#pragma unroll
    for (int i = 0; i < 4; ++i)
#pragma unroll
        for (int j = 0; j < 4; ++j) acc[i][j] = (f32x4){0.f, 0.f, 0.f, 0.f};

    for (int kt = 0; kt < KTILES; ++kt) {
        const int k0 = kt * 32;
        __syncthreads();   // previous tile's compute done before overwrite

        // ---- B staging: 4 rounds x {hi,lo}, pure global_load_lds ----
#pragma unroll
        for (int c = 0; c < 4; ++c) {
            const size_t goff = (size_t)(bcol0 + 64 * c) * KPAD + k0 + akc * 8;
            __builtin_amdgcn_global_load_lds(
                (const __attribute__((address_space(1))) void*)(Wh + goff),
                (__attribute__((address_space(3))) void*)(bh_dst + c * 4096),
                16, 0, 0);
            __builtin_amdgcn_global_load_lds(
                (const __attribute__((address_space(1))) void*)(Wl + goff),
                (__attribute__((address_space(3))) void*)(bl_dst + c * 4096),
                16, 0, 0);
        }

        // ---- A staging: 8 scalar x loads (rows are only 4B aligned),
        //      split to bf16 hi/lo, two ds_write_b128 ----
        float av[8];
#pragma unroll
        for (int j = 0; j < 8; ++j) {
            const int gk = k0 + akc * 8 + j;
            av[j] = (rok && gk < NUM_INPUT) ? xrow[k0 + j] : 0.f;
        }
        short8 vh, vl;
#pragma unroll
        for (int j = 0; j < 8; ++j) {
            const unsigned short h = f2bf(av[j]);
            vh[j] = (short)h;
            vl[j] = (short)f2bf(av[j] - bf2f(h));
        }
        *(short8*)ah_dst = vh;
        *(short8*)al_dst = vl;

        __syncthreads();   // drains vmcnt (gload_lds) + lgkmcnt (ds_write)

        // ---- compute: 48 MFMAs ----
        short8 ahf[4], alf[4];
#pragma unroll
        for (int mb = 0; mb < 4; ++mb) {
            ahf[mb] = *(const short8*)&Ah[mb * 16 + fr][fg * 8];
            alf[mb] = *(const short8*)&Al[mb * 16 + fr][fg * 8];
        }
#pragma unroll
        for (int nb = 0; nb < 4; ++nb) {
            const int col = wv * 64 + nb * 16 + fr;
            const short8 bhf = *(const short8*)&Bh[col][fg * 8];
            const short8 blf = *(const short8*)&Bl[col][fg * 8];
#pragma unroll
            for (int mb = 0; mb < 4; ++mb) {
                acc[mb][nb] = __builtin_amdgcn_mfma_f32_16x16x32_bf16(
                    alf[mb], bhf, acc[mb][nb], 0, 0, 0);
                acc[mb][nb] = __builtin_amdgcn_mfma_f32_16x16x32_bf16(
                    ahf[mb], blf, acc[mb][nb], 0, 0, 0);
                acc[mb][nb] = __builtin_amdgcn_mfma_f32_16x16x32_bf16(
                    ahf[mb], bhf, acc[mb][nb], 0, 0, 0);
            }
        }
    }

    // D layout (m89-verified): col = lane&15, row = (lane>>4)*4 + reg
#pragma unroll
    for (int mb = 0; mb < 4; ++mb) {
        const int row = m0 + mb * 16 + fg * 4;
#pragma unroll
        for (int r = 0; r < 4; ++r) {
            if (row + r < N_NODES) {
#pragma unroll
                for (int nb = 0; nb < 4; ++nb)
                    support[(size_t)(row + r) * NUM_DIM + wv * 64 + nb * 16 + fr] =
                        acc[mb][nb][r];
            }
        }
    }
}

// ---------------------------------------------------------------------------
// scatter1: agg[dst[e], :] += support[src[e], :] * w[e].
// 4 edges per 256-thread block; one wave per edge, float4 per lane.
// ---------------------------------------------------------------------------
__global__ __launch_bounds__(256) void scatter1_kernel(
    const float* __restrict__ support, const int* __restrict__ src,
    const int* __restrict__ dst, const float* __restrict__ w,
    float* __restrict__ agg)
{
    const int e    = blockIdx.x * 4 + (threadIdx.x >> 6);
    const int lane = threadIdx.x & 63;
    const int s  = src[e];
    const int tt = dst[e];
    const float we = w[e];
    const float4 v = *(const float4*)&support[(size_t)s * NUM_DIM + lane * 4];
    float* ap = &agg[(size_t)tt * NUM_DIM + lane * 4];
    atomicAdd(ap + 0, v.x * we);
    atomicAdd(ap + 1, v.y * we);
    atomicAdd(ap + 2, v.z * we);
    atomicAdd(ap + 3, v.w * we);
}

// ---------------------------------------------------------------------------
// act: h = leaky_relu(agg + b1), in place.
// ---------------------------------------------------------------------------
__global__ __launch_bounds__(256) void act_kernel(
    float* __restrict__ agg, const float* __restrict__ b1)
{
    int i = blockIdx.x * 256 + threadIdx.x;
    if (i >= N_NODES * NUM_DIM) return;
    float v = agg[i] + b1[i & (NUM_DIM - 1)];
    agg[i] = (v > 0.f) ? v : 0.01f * v;
}

// ---------------------------------------------------------------------------
// GEMM2: support2 = h @ W2  (256 -> 6). One wave per node.
// ---------------------------------------------------------------------------
__global__ __launch_bounds__(256) void gemm2_kernel(
    const float* __restrict__ h, const float* __restrict__ W2,
    float* __restrict__ support2)
{
    int gid  = blockIdx.x * 256 + threadIdx.x;
    int node = gid >> 6;
    int lane = gid & 63;
    if (node >= N_NODES) return;
    float4 hv = *(const float4*)&h[(size_t)node * NUM_DIM + lane * 4];
    const float hvv[4] = {hv.x, hv.y, hv.z, hv.w};
    float o[NUM_OUT];
#pragma unroll
    for (int j = 0; j < NUM_OUT; ++j) o[j] = 0.f;
#pragma unroll
    for (int c = 0; c < 4; ++c) {
        int k = lane * 4 + c;
#pragma unroll
        for (int j = 0; j < NUM_OUT; ++j)
            o[j] += hvv[c] * W2[k * NUM_OUT + j];
    }
#pragma unroll
    for (int j = 0; j < NUM_OUT; ++j) {
#pragma unroll
        for (int off = 32; off > 0; off >>= 1)
            o[j] += __shfl_down(o[j], off);
    }
    if (lane == 0) {
#pragma unroll
        for (int j = 0; j < NUM_OUT; ++j)
            support2[(size_t)node * NUM_OUT + j] = o[j];
    }
}

// ---------------------------------------------------------------------------
// scatter2: out[dst[e], :] += support2[src[e], :] * w[e]  (6 dims/edge).
// ---------------------------------------------------------------------------
__global__ __launch_bounds__(256) void scatter2_kernel(
    const float* __restrict__ support2, const int* __restrict__ src,
    const int* __restrict__ dst, const float* __restrict__ w,
    float* __restrict__ out)
{
    int e = blockIdx.x * 256 + threadIdx.x;
    if (e >= N_EDGES) return;
    int s = src[e];
    int tt = dst[e];
    float we = w[e];
#pragma unroll
    for (int j = 0; j < NUM_OUT; ++j)
        atomicAdd(&out[(size_t)tt * NUM_OUT + j], support2[(size_t)s * NUM_OUT + j] * we);
}

// ---------------------------------------------------------------------------
// lsm: out = log_softmax(out + b2, axis=1), in place.
// ---------------------------------------------------------------------------
__global__ __launch_bounds__(256) void lsm_kernel(
    float* __restrict__ out, const float* __restrict__ b2)
{
    int n = blockIdx.x * 256 + threadIdx.x;
    if (n >= N_NODES) return;
    float v[NUM_OUT];
    float m = -1e30f;
#pragma unroll
    for (int j = 0; j < NUM_OUT; ++j) {
        v[j] = out[n * NUM_OUT + j] + b2[j];
        m = fmaxf(m, v[j]);
    }
    float s = 0.f;
#pragma unroll
    for (int j = 0; j < NUM_OUT; ++j) s += expf(v[j] - m);
    float ls = logf(s);
#pragma unroll
    for (int j = 0; j < NUM_OUT; ++j) out[n * NUM_OUT + j] = v[j] - m - ls;
}

extern "C" void kernel_launch(void* const* d_in, const int* in_sizes, int n_in,
                              void* d_out, int out_size, void* d_ws, size_t ws_size,
                              hipStream_t stream)
{
    const float* x   = (const float*)d_in[0];
    const int*   src = (const int*)  d_in[1];
    const int*   dst = (const int*)  d_in[2];
    const float* w   = (const float*)d_in[3];
    const float* W1  = (const float*)d_in[4];
    const float* b1  = (const float*)d_in[5];
    const float* W2  = (const float*)d_in[6];
    const float* b2  = (const float*)d_in[7];
    float* out = (float*)d_out;

    // Workspace layout (bytes):
    //   support1: [0, 51,200,000)            50000*256 f32
    //   agg1:     [51,200,000, 102,400,000)  50000*256 f32
    //   support2: [102,400,000, 103,600,000) 50000*6  f32
    //   W1t_hi:   [103,600,000, 105,500,544) 256*3712 bf16 (transposed, padded)
    //   W1t_lo:   [105,500,544, 107,401,088) 256*3712 bf16
    char* ws = (char*)d_ws;
    float*          support1 = (float*)(ws);
    float*          agg1     = (float*)(ws + 51200000);
    float*          support2 = (float*)(ws + 102400000);
    unsigned short* W1t_hi   = (unsigned short*)(ws + 103600000);
    unsigned short* W1t_lo   = (unsigned short*)(ws + 105500544);

    hipMemsetAsync(agg1, 0, (size_t)N_NODES * NUM_DIM * sizeof(float), stream);
    hipMemsetAsync(out,  0, (size_t)N_NODES * NUM_OUT * sizeof(float), stream);

    w1_split_kernel<<<dim3((NUM_DIM * KPAD + 255) / 256), 256, 0, stream>>>(
        W1, W1t_hi, W1t_lo);
    gemm1_kernel<<<dim3((N_NODES + 63) / 64), 256, 0, stream>>>(
        x, W1t_hi, W1t_lo, support1);
    scatter1_kernel<<<dim3(N_EDGES / 4), 256, 0, stream>>>(support1, src, dst, w, agg1);
    act_kernel<<<dim3((N_NODES * NUM_DIM + 255) / 256), 256, 0, stream>>>(agg1, b1);
    gemm2_kernel<<<dim3((N_NODES * 64) / 256), 256, 0, stream>>>(agg1, W2, support2);
    scatter2_kernel<<<dim3((N_EDGES + 255) / 256), 256, 0, stream>>>(support2, src, dst, w, out);
    lsm_kernel<<<dim3((N_NODES + 255) / 256), 256, 0, stream>>>(out, b2);
}

// Round 2
// 1667.119 us; speedup vs baseline: 3.2491x; 1.7720x over previous
//
#include <hip/hip_runtime.h>
#include <math.h>

#define N_NODES   50000
#define N_EDGES   400000
#define NUM_INPUT 3703
#define NUM_DIM   256
#define NUM_OUT   6

#define KPAD   3712      // 116 * 32, zero-padded K for W1 split arrays
#define KTILES 116

typedef __attribute__((ext_vector_type(8))) short short8;
typedef __attribute__((ext_vector_type(4))) float f32x4;

// fp32 -> bf16 (round-to-nearest-even), manual so behavior is explicit
static __device__ __forceinline__ unsigned short f2bf(float f) {
    unsigned u = __float_as_uint(f);
    u += 0x7fffu + ((u >> 16) & 1u);
    return (unsigned short)(u >> 16);
}
static __device__ __forceinline__ float bf2f(unsigned short h) {
    return __uint_as_float(((unsigned)h) << 16);
}

// ---------------------------------------------------------------------------
// w1_split: W1[k][col] -> W1t_hi/lo[col][k] (bf16, transposed, K zero-padded).
// ---------------------------------------------------------------------------
__global__ __launch_bounds__(256) void w1_split_kernel(
    const float* __restrict__ W1,
    unsigned short* __restrict__ Wh, unsigned short* __restrict__ Wl)
{
    int idx = blockIdx.x * 256 + threadIdx.x;      // [0, 256*3712)
    if (idx >= NUM_DIM * KPAD) return;
    int col = idx / KPAD;
    int k   = idx - col * KPAD;
    float v = (k < NUM_INPUT) ? W1[(size_t)k * NUM_DIM + col] : 0.f;
    unsigned short h = f2bf(v);
    Wh[idx] = h;
    Wl[idx] = f2bf(v - bf2f(h));
}

// ---------------------------------------------------------------------------
// CSR build: group edges by dst.  deg -> exclusive scan -> slot fill.
// ---------------------------------------------------------------------------
__global__ __launch_bounds__(256) void deg_count_kernel(
    const int* __restrict__ dst, int* __restrict__ deg)
{
    int e = blockIdx.x * 256 + threadIdx.x;
    if (e >= N_EDGES) return;
    atomicAdd(&deg[dst[e]], 1);
}

// Single-block exclusive scan over 50000 degrees. Writes row_ptr[0..N] and
// initializes cursor[] (= row_ptr[i]) for the fill pass.
__global__ __launch_bounds__(1024) void scan_kernel(
    const int* __restrict__ deg, int* __restrict__ row_ptr,
    int* __restrict__ cursor)
{
    __shared__ int buf[1024];
    __shared__ int carry_s;
    const int tid = threadIdx.x;
    if (tid == 0) carry_s = 0;
    __syncthreads();
    for (int base = 0; base < N_NODES; base += 1024) {
        const int i = base + tid;
        const int v = (i < N_NODES) ? deg[i] : 0;
        buf[tid] = v;
        __syncthreads();
#pragma unroll
        for (int off = 1; off < 1024; off <<= 1) {
            int t = (tid >= off) ? buf[tid - off] : 0;
            __syncthreads();
            buf[tid] += t;
            __syncthreads();
        }
        const int c = carry_s;
        if (i < N_NODES) {
            const int excl = c + buf[tid] - v;
            row_ptr[i] = excl;
            cursor[i]  = excl;
        }
        const int tot = buf[1023];
        __syncthreads();
        if (tid == 0) carry_s = c + tot;
        __syncthreads();
    }
    if (tid == 0) row_ptr[N_NODES] = carry_s;   // == N_EDGES
}

__global__ __launch_bounds__(256) void fill_kernel(
    const int* __restrict__ dst, int* __restrict__ cursor,
    int* __restrict__ edge_idx)
{
    int e = blockIdx.x * 256 + threadIdx.x;
    if (e >= N_EDGES) return;
    int pos = atomicAdd(&cursor[dst[e]], 1);
    edge_idx[pos] = e;
}

// ---------------------------------------------------------------------------
// GEMM1 (MFMA, split-bf16): support = x @ W1.  M=50000, K=3703, N=256.
// (unchanged from previous round — see its counters before touching)
// ---------------------------------------------------------------------------
__global__ __launch_bounds__(256) void gemm1_kernel(
    const float* __restrict__ x,
    const unsigned short* __restrict__ Wh, const unsigned short* __restrict__ Wl,
    float* __restrict__ support)
{
    __shared__ unsigned short Ah[64][32];    // 4 KB  [row][k]
    __shared__ unsigned short Al[64][32];    // 4 KB
    __shared__ unsigned short Bh[256][32];   // 16 KB [col][k]
    __shared__ unsigned short Bl[256][32];   // 16 KB

    const int t    = threadIdx.x;
    const int lane = t & 63;
    const int wv   = t >> 6;                 // wave 0..3 -> col block
    const int m0   = blockIdx.x * 64;

    const int arow = t >> 2;                 // staging: row 0..63
    const int akc  = t & 3;                  // staging: k-chunk 0..3 (8 elems)
    const int fr   = lane & 15;              // frag row (A) / col (B,D)
    const int fg   = lane >> 4;              // frag k-group 0..3

    const int gr   = m0 + arow;
    const bool rok = (gr < N_NODES);
    const float* xrow = x + (size_t)gr * NUM_INPUT + akc * 8;

    char* ah_dst = (char*)&Ah[0][0] + t * 16;
    char* al_dst = (char*)&Al[0][0] + t * 16;
    char* bh_dst = (char*)&Bh[0][0] + t * 16;
    char* bl_dst = (char*)&Bl[0][0] + t * 16;
    const int bcol0 = t >> 2;                // B staging col (+64 per round)

    f32x4 acc[4][4];
#pragma unroll
    for (int i = 0; i < 4; ++i)
#pragma unroll
        for (int j = 0; j < 4; ++j) acc[i][j] = (f32x4){0.f, 0.f, 0.f, 0.f};

    for (int kt = 0; kt < KTILES; ++kt) {
        const int k0 = kt * 32;
        __syncthreads();

#pragma unroll
        for (int c = 0; c < 4; ++c) {
            const size_t goff = (size_t)(bcol0 + 64 * c) * KPAD + k0 + akc * 8;
            __builtin_amdgcn_global_load_lds(
                (const __attribute__((address_space(1))) void*)(Wh + goff),
                (__attribute__((address_space(3))) void*)(bh_dst + c * 4096),
                16, 0, 0);
            __builtin_amdgcn_global_load_lds(
                (const __attribute__((address_space(1))) void*)(Wl + goff),
                (__attribute__((address_space(3))) void*)(bl_dst + c * 4096),
                16, 0, 0);
        }

        float av[8];
#pragma unroll
        for (int j = 0; j < 8; ++j) {
            const int gk = k0 + akc * 8 + j;
            av[j] = (rok && gk < NUM_INPUT) ? xrow[k0 + j] : 0.f;
        }
        short8 vh, vl;
#pragma unroll
        for (int j = 0; j < 8; ++j) {
            const unsigned short h = f2bf(av[j]);
            vh[j] = (short)h;
            vl[j] = (short)f2bf(av[j] - bf2f(h));
        }
        *(short8*)ah_dst = vh;
        *(short8*)al_dst = vl;

        __syncthreads();

        short8 ahf[4], alf[4];
#pragma unroll
        for (int mb = 0; mb < 4; ++mb) {
            ahf[mb] = *(const short8*)&Ah[mb * 16 + fr][fg * 8];
            alf[mb] = *(const short8*)&Al[mb * 16 + fr][fg * 8];
        }
#pragma unroll
        for (int nb = 0; nb < 4; ++nb) {
            const int col = wv * 64 + nb * 16 + fr;
            const short8 bhf = *(const short8*)&Bh[col][fg * 8];
            const short8 blf = *(const short8*)&Bl[col][fg * 8];
#pragma unroll
            for (int mb = 0; mb < 4; ++mb) {
                acc[mb][nb] = __builtin_amdgcn_mfma_f32_16x16x32_bf16(
                    alf[mb], bhf, acc[mb][nb], 0, 0, 0);
                acc[mb][nb] = __builtin_amdgcn_mfma_f32_16x16x32_bf16(
                    ahf[mb], blf, acc[mb][nb], 0, 0, 0);
                acc[mb][nb] = __builtin_amdgcn_mfma_f32_16x16x32_bf16(
                    ahf[mb], bhf, acc[mb][nb], 0, 0, 0);
            }
        }
    }

#pragma unroll
    for (int mb = 0; mb < 4; ++mb) {
        const int row = m0 + mb * 16 + fg * 4;
#pragma unroll
        for (int r = 0; r < 4; ++r) {
            if (row + r < N_NODES) {
#pragma unroll
                for (int nb = 0; nb < 4; ++nb)
                    support[(size_t)(row + r) * NUM_DIM + wv * 64 + nb * 16 + fr] =
                        acc[mb][nb][r];
            }
        }
    }
}

// ---------------------------------------------------------------------------
// agg1_fused: per dst node (one wave each, 4 nodes/block):
//   hv   = leaky_relu( sum_{e in CSR[node]} support[src[e]]*w[e]  + b1 )
//   support2[node][j] = sum_k hv[k] * W2[k][j]        (W2 staged in LDS)
// Gather reads are coalesced 1KB bursts from an L3-resident 51.2MB array;
// writes are 24B per node. No atomics. Kills act/gemm2/h entirely.
// ---------------------------------------------------------------------------
__global__ __launch_bounds__(256) void agg1_fused_kernel(
    const float* __restrict__ support, const int* __restrict__ row_ptr,
    const int* __restrict__ edge_idx, const int* __restrict__ src,
    const float* __restrict__ w, const float* __restrict__ b1,
    const float* __restrict__ W2, float* __restrict__ support2)
{
    __shared__ float W2s[NUM_DIM][NUM_OUT];   // 6 KB
    const int t = threadIdx.x;
#pragma unroll
    for (int j = 0; j < NUM_OUT; ++j) W2s[t][j] = W2[t * NUM_OUT + j];
    __syncthreads();

    const int node = blockIdx.x * 4 + (t >> 6);
    const int lane = t & 63;
    if (node >= N_NODES) return;

    const int p0 = row_ptr[node], p1 = row_ptr[node + 1];
    float4 acc = make_float4(0.f, 0.f, 0.f, 0.f);
    for (int p = p0; p < p1; ++p) {
        const int e = edge_idx[p];           // wave-uniform -> broadcast
        const float we = w[e];
        const float4 v = *(const float4*)&support[(size_t)src[e] * NUM_DIM + lane * 4];
        acc.x += v.x * we; acc.y += v.y * we;
        acc.z += v.z * we; acc.w += v.w * we;
    }
    const float4 bv = *(const float4*)&b1[lane * 4];
    float hv[4];
    hv[0] = acc.x + bv.x; hv[1] = acc.y + bv.y;
    hv[2] = acc.z + bv.z; hv[3] = acc.w + bv.w;
#pragma unroll
    for (int c = 0; c < 4; ++c) hv[c] = (hv[c] > 0.f) ? hv[c] : 0.01f * hv[c];

    float o[NUM_OUT];
#pragma unroll
    for (int j = 0; j < NUM_OUT; ++j) o[j] = 0.f;
#pragma unroll
    for (int c = 0; c < 4; ++c) {
        const int k = lane * 4 + c;
#pragma unroll
        for (int j = 0; j < NUM_OUT; ++j) o[j] += hv[c] * W2s[k][j];
    }
#pragma unroll
    for (int j = 0; j < NUM_OUT; ++j) {
#pragma unroll
        for (int off = 32; off > 0; off >>= 1)
            o[j] += __shfl_down(o[j], off);
    }
    if (lane == 0) {
#pragma unroll
        for (int j = 0; j < NUM_OUT; ++j)
            support2[(size_t)node * NUM_OUT + j] = o[j];
    }
}

// ---------------------------------------------------------------------------
// agg2_fused: per dst node (one wave each):
//   v[j] = sum_{e} support2[src[e]][j]*w[e] + b2[j];  out = log_softmax(v).
// support2 is 1.2MB -> L2-resident gather. Kills scatter2 + lsm + memsets.
// ---------------------------------------------------------------------------
__global__ __launch_bounds__(256) void agg2_fused_kernel(
    const float* __restrict__ support2, const int* __restrict__ row_ptr,
    const int* __restrict__ edge_idx, const int* __restrict__ src,
    const float* __restrict__ w, const float* __restrict__ b2,
    float* __restrict__ out)
{
    const int t    = threadIdx.x;
    const int node = blockIdx.x * 4 + (t >> 6);
    const int lane = t & 63;
    if (node >= N_NODES) return;

    const int p0 = row_ptr[node], p1 = row_ptr[node + 1];
    float o[NUM_OUT];
#pragma unroll
    for (int j = 0; j < NUM_OUT; ++j) o[j] = 0.f;
    for (int p = p0 + lane; p < p1; p += 64) {
        const int e = edge_idx[p];
        const float we = w[e];
        const float* sp = &support2[(size_t)src[e] * NUM_OUT];
#pragma unroll
        for (int j = 0; j < NUM_OUT; ++j) o[j] += sp[j] * we;
    }
#pragma unroll
    for (int j = 0; j < NUM_OUT; ++j) {
#pragma unroll
        for (int off = 32; off > 0; off >>= 1)
            o[j] += __shfl_down(o[j], off);
    }
    if (lane == 0) {
        float v[NUM_OUT];
        float m = -1e30f;
#pragma unroll
        for (int j = 0; j < NUM_OUT; ++j) {
            v[j] = o[j] + b2[j];
            m = fmaxf(m, v[j]);
        }
        float s = 0.f;
#pragma unroll
        for (int j = 0; j < NUM_OUT; ++j) s += expf(v[j] - m);
        const float ls = logf(s);
#pragma unroll
        for (int j = 0; j < NUM_OUT; ++j)
            out[(size_t)node * NUM_OUT + j] = v[j] - m - ls;
    }
}

extern "C" void kernel_launch(void* const* d_in, const int* in_sizes, int n_in,
                              void* d_out, int out_size, void* d_ws, size_t ws_size,
                              hipStream_t stream)
{
    const float* x   = (const float*)d_in[0];
    const int*   src = (const int*)  d_in[1];
    const int*   dst = (const int*)  d_in[2];
    const float* w   = (const float*)d_in[3];
    const float* W1  = (const float*)d_in[4];
    const float* b1  = (const float*)d_in[5];
    const float* W2  = (const float*)d_in[6];
    const float* b2  = (const float*)d_in[7];
    float* out = (float*)d_out;

    // Workspace layout (bytes):
    //   support1:  [0,          51,200,000)   50000*256 f32
    //   support2:  [51,200,000, 52,400,000)   50000*6  f32
    //   W1t_hi:    [52,400,000, 54,300,544)   256*3712 bf16
    //   W1t_lo:    [54,300,544, 56,201,088)   256*3712 bf16
    //   deg/cursor:[56,201,088, 56,401,088)   50000 i32
    //   row_ptr:   [56,401,088, 56,601,092)   50001 i32
    //   edge_idx:  [56,601,092, 58,201,092)   400000 i32
    char* ws = (char*)d_ws;
    float*          support1 = (float*)(ws);
    float*          support2 = (float*)(ws + 51200000);
    unsigned short* W1t_hi   = (unsigned short*)(ws + 52400000);
    unsigned short* W1t_lo   = (unsigned short*)(ws + 54300544);
    int*            deg_cur  = (int*)(ws + 56201088);
    int*            row_ptr  = (int*)(ws + 56401088);
    int*            edge_idx = (int*)(ws + 56601092);

    hipMemsetAsync(deg_cur, 0, (size_t)N_NODES * sizeof(int), stream);

    // CSR build (independent of gemm1; stream-serial anyway)
    deg_count_kernel<<<dim3((N_EDGES + 255) / 256), 256, 0, stream>>>(dst, deg_cur);
    scan_kernel<<<dim3(1), 1024, 0, stream>>>(deg_cur, row_ptr, deg_cur);
    fill_kernel<<<dim3((N_EDGES + 255) / 256), 256, 0, stream>>>(dst, deg_cur, edge_idx);

    w1_split_kernel<<<dim3((NUM_DIM * KPAD + 255) / 256), 256, 0, stream>>>(
        W1, W1t_hi, W1t_lo);
    gemm1_kernel<<<dim3((N_NODES + 63) / 64), 256, 0, stream>>>(
        x, W1t_hi, W1t_lo, support1);
    agg1_fused_kernel<<<dim3((N_NODES + 3) / 4), 256, 0, stream>>>(
        support1, row_ptr, edge_idx, src, w, b1, W2, support2);
    agg2_fused_kernel<<<dim3((N_NODES + 3) / 4), 256, 0, stream>>>(
        support2, row_ptr, edge_idx, src, w, b2, out);
}

// Round 4
// 1545.365 us; speedup vs baseline: 3.5051x; 1.0788x over previous
//
#include <hip/hip_runtime.h>
#include <math.h>

#define N_NODES   50000
#define N_EDGES   400000
#define NUM_INPUT 3703
#define NUM_DIM   256
#define NUM_OUT   6

#define KPAD   3712      // 116 * 32
#define KTILES 116

typedef __attribute__((ext_vector_type(8))) short short8;
typedef __attribute__((ext_vector_type(4))) float f32x4;

// fp32 -> bf16 round-to-nearest-even
static __device__ __forceinline__ unsigned short f2bf_rne(float f) {
    unsigned u = __float_as_uint(f);
    u += 0x7fffu + ((u >> 16) & 1u);
    return (unsigned short)(u >> 16);
}

// ---------------------------------------------------------------------------
// w1_img: build the PRE-SWIZZLED bf16 hi/lo image of W1^T, in exactly the
// LDS layout gemm1 wants.  Per k-tile kt: a 32 KB block at byte kt*32768:
//   [0,16KB):   hi chunks — chunk (col, slot) at byte col*64 + ((slot+(col>>1))&3)*16
//   [16KB,32KB): lo chunks, same placement.
// Chunk (col,slot) holds bf16 of W1[kt*32+slot*8 + (0..7)][col].
// gemm1's B staging is then a fully LINEAR global_load_lds copy (rule 21:
// source pre-swizzled, LDS dest linear, reads swizzled).
// ---------------------------------------------------------------------------
__global__ __launch_bounds__(256) void w1_img_kernel(
    const float* __restrict__ W1, unsigned short* __restrict__ img)
{
    int cg = blockIdx.x * 256 + threadIdx.x;       // global hi-chunk id
    if (cg >= KTILES * 1024) return;
    int kt   = cg >> 10;
    int cc   = cg & 1023;                          // chunk within tile image
    int col  = cc >> 2;
    int spos = cc & 3;                             // physical slot position
    int slot = (spos - (col >> 1)) & 3;            // logical k-slot stored here
    int k0   = kt * 32 + slot * 8;
    size_t base = (size_t)kt * 16384 + (size_t)cc * 8;   // in shorts
    short8 vh, vl;
#pragma unroll
    for (int j = 0; j < 8; ++j) {
        int k = k0 + j;
        float v = (k < NUM_INPUT) ? W1[(size_t)k * NUM_DIM + col] : 0.f;
        unsigned u = __float_as_uint(v);
        vh[j] = (short)(u >> 16);                          // truncation hi
        float rec = __uint_as_float(u & 0xffff0000u);
        vl[j] = (short)f2bf_rne(v - rec);                  // exact residual, RNE
    }
    *(short8*)(img + base)        = vh;
    *(short8*)(img + base + 8192) = vl;                    // lo half of tile
}

// ---------------------------------------------------------------------------
// CSR build: deg -> shuffle-scan -> fill (writes SORTED src/w payloads so the
// agg kernels have no edge_idx indirection).
// ---------------------------------------------------------------------------
__global__ __launch_bounds__(256) void deg_count_kernel(
    const int* __restrict__ dst, int* __restrict__ deg)
{
    int e = blockIdx.x * 256 + threadIdx.x;
    if (e >= N_EDGES) return;
    atomicAdd(&deg[dst[e]], 1);
}

__global__ __launch_bounds__(1024) void scan_kernel(
    const int* __restrict__ deg, int* __restrict__ row_ptr,
    int* __restrict__ cursor)
{
    __shared__ int wsum[16];
    __shared__ int carry_s;
    const int tid = threadIdx.x, lane = tid & 63, wid = tid >> 6;
    if (tid == 0) carry_s = 0;
    __syncthreads();
    for (int base = 0; base < N_NODES; base += 1024) {
        const int i = base + tid;
        const int v = (i < N_NODES) ? deg[i] : 0;
        int x = v;                                  // inclusive wave scan
#pragma unroll
        for (int off = 1; off < 64; off <<= 1) {
            int y = __shfl_up(x, off);
            if (lane >= off) x += y;
        }
        if (lane == 63) wsum[wid] = x;
        __syncthreads();
        if (wid == 0) {                             // scan the 16 wave sums
            int s = (lane < 16) ? wsum[lane] : 0;
#pragma unroll
            for (int off = 1; off < 16; off <<= 1) {
                int y = __shfl_up(s, off);
                if (lane >= off) s += y;
            }
            if (lane < 16) wsum[lane] = s;
        }
        __syncthreads();
        const int wpre  = (wid == 0) ? 0 : wsum[wid - 1];
        const int carry = carry_s;
        const int incl  = carry + wpre + x;
        if (i < N_NODES) { row_ptr[i] = incl - v; cursor[i] = incl - v; }
        __syncthreads();                            // everyone read carry_s
        if (tid == 1023) carry_s = incl;
        __syncthreads();
    }
    if (threadIdx.x == 0) row_ptr[N_NODES] = carry_s;   // == N_EDGES
}

__global__ __launch_bounds__(256) void fill_kernel(
    const int* __restrict__ dst, const int* __restrict__ src,
    const float* __restrict__ w, int* __restrict__ cursor,
    int* __restrict__ src_s, float* __restrict__ w_s)
{
    int e = blockIdx.x * 256 + threadIdx.x;
    if (e >= N_EDGES) return;
    int pos = atomicAdd(&cursor[dst[e]], 1);
    src_s[pos] = src[e];
    w_s[pos]   = w[e];
}

// ---------------------------------------------------------------------------
// GEMM1 (MFMA split-bf16, double-buffered): support = x @ W1.
// 64 rows x 256 cols per block, 4 waves, K-tile 32, LDS 80KB -> 2 blocks/CU.
// Pipeline per tile: issue x-loads(t+1) [oldest vmcnt] -> issue B gload_lds
// (t+1, linear copy of pre-swizzled image) -> 16 ds_read + 48 MFMA on tile t
// -> convert+ds_write A(t+1) -> one barrier.  All LDS accesses 2-way max.
// ---------------------------------------------------------------------------
__global__ __launch_bounds__(256) void gemm1_kernel(
    const float* __restrict__ x, const unsigned short* __restrict__ Wimg,
    float* __restrict__ support)
{
    __shared__ unsigned short Abuf[2][4096];    //  8 KB/buf: hi[0,2048) lo[2048,4096)
    __shared__ unsigned short Bbuf[2][16384];   // 32 KB/buf: hi[0,8192) lo[8192,16384)

    const int t    = threadIdx.x;
    const int lane = t & 63;
    const int wv   = t >> 6;
    const int m0   = blockIdx.x * 64;

    const int arow = t >> 2;                 // A staging: row 0..63
    const int akc  = t & 3;                  // A staging: k-slot 0..3 (8 elems)
    const int fr   = lane & 15;
    const int fg   = lane >> 4;

    const int gr   = m0 + arow;
    const bool rok = (gr < N_NODES);
    const float* xbase = x + (size_t)(rok ? gr : 0) * NUM_INPUT + akc * 8;

    // swizzled placement: chunk (row,slot) at short-off row*32 + ((slot+(row>>1))&3)*8
    const int a_woff = arow * 32 + ((akc + (arow >> 1)) & 3) * 8;
    const int aslot  = ((fg + (fr >> 1)) & 3) * 8;   // reader slot offset (A and B)

    f32x4 acc[4][4];
#pragma unroll
    for (int i = 0; i < 4; ++i)
#pragma unroll
        for (int j = 0; j < 4; ++j) acc[i][j] = (f32x4){0.f, 0.f, 0.f, 0.f};

    float av[8];

    // ---- prologue: stage tile 0 ----
#pragma unroll
    for (int j = 0; j < 8; ++j)
        av[j] = rok ? xbase[j] : 0.f;        // kt=0: all k in bounds
    {
        const unsigned short* wsrc = Wimg + (size_t)t * 8;
        unsigned short* bdst = &Bbuf[0][t * 8];
#pragma unroll
        for (int r = 0; r < 8; ++r)
            __builtin_amdgcn_global_load_lds(
                (const __attribute__((address_space(1))) void*)(wsrc + r * 2048),
                (__attribute__((address_space(3))) void*)(bdst + r * 2048),
                16, 0, 0);
    }
    {
        short8 vh, vl;
#pragma unroll
        for (int j = 0; j < 8; ++j) {
            unsigned u = __float_as_uint(av[j]);
            vh[j] = (short)(u >> 16);
            float rec = __uint_as_float(u & 0xffff0000u);
            vl[j] = (short)f2bf_rne(av[j] - rec);
        }
        *(short8*)(&Abuf[0][a_woff])        = vh;
        *(short8*)(&Abuf[0][2048 + a_woff]) = vl;
    }
    __syncthreads();

    int buf = 0;
    for (int kt = 0; kt < KTILES; ++kt) {
        const int nxt = kt + 1;
        if (nxt < KTILES) {
            // x loads FIRST (oldest vmcnt -> counted wait leaves B gloads in flight)
            const float* xk = xbase + nxt * 32;
            const int kb = nxt * 32 + akc * 8;
#pragma unroll
            for (int j = 0; j < 8; ++j)
                av[j] = (rok && (kb + j) < NUM_INPUT) ? xk[j] : 0.f;
            const unsigned short* wsrc = Wimg + (size_t)nxt * 16384 + t * 8;
            unsigned short* bdst = &Bbuf[buf ^ 1][t * 8];
#pragma unroll
            for (int r = 0; r < 8; ++r)
                __builtin_amdgcn_global_load_lds(
                    (const __attribute__((address_space(1))) void*)(wsrc + r * 2048),
                    (__attribute__((address_space(3))) void*)(bdst + r * 2048),
                    16, 0, 0);
        }

        // ---- compute tile kt from buf ----
        const unsigned short* A = Abuf[buf];
        const unsigned short* B = Bbuf[buf];
        short8 ahf[4], alf[4];
#pragma unroll
        for (int mb = 0; mb < 4; ++mb) {
            const int ro = (mb * 16 + fr) * 32 + aslot;
            ahf[mb] = *(const short8*)(A + ro);
            alf[mb] = *(const short8*)(A + 2048 + ro);
        }
#pragma unroll
        for (int nb = 0; nb < 4; ++nb) {
            const int co = (wv * 64 + nb * 16 + fr) * 32 + aslot;
            const short8 bhf = *(const short8*)(B + co);
            const short8 blf = *(const short8*)(B + 8192 + co);
#pragma unroll
            for (int mb = 0; mb < 4; ++mb) {
                acc[mb][nb] = __builtin_amdgcn_mfma_f32_16x16x32_bf16(
                    alf[mb], bhf, acc[mb][nb], 0, 0, 0);
                acc[mb][nb] = __builtin_amdgcn_mfma_f32_16x16x32_bf16(
                    ahf[mb], blf, acc[mb][nb], 0, 0, 0);
                acc[mb][nb] = __builtin_amdgcn_mfma_f32_16x16x32_bf16(
                    ahf[mb], bhf, acc[mb][nb], 0, 0, 0);
            }
        }

        if (nxt < KTILES) {
            short8 vh, vl;
#pragma unroll
            for (int j = 0; j < 8; ++j) {
                unsigned u = __float_as_uint(av[j]);
                vh[j] = (short)(u >> 16);
                float rec = __uint_as_float(u & 0xffff0000u);
                vl[j] = (short)f2bf_rne(av[j] - rec);
            }
            unsigned short* ad = &Abuf[buf ^ 1][0];
            *(short8*)(ad + a_woff)        = vh;
            *(short8*)(ad + 2048 + a_woff) = vl;
        }
        __syncthreads();
        buf ^= 1;
    }

    // D layout: col = lane&15, row = (lane>>4)*4 + reg
#pragma unroll
    for (int mb = 0; mb < 4; ++mb) {
        const int row = m0 + mb * 16 + fg * 4;
#pragma unroll
        for (int r = 0; r < 4; ++r) {
            if (row + r < N_NODES) {
#pragma unroll
                for (int nb = 0; nb < 4; ++nb)
                    support[(size_t)(row + r) * NUM_DIM + wv * 64 + nb * 16 + fr] =
                        acc[mb][nb][r];
            }
        }
    }
}

// ---------------------------------------------------------------------------
// agg1_fused: per dst node (one wave, 4 nodes/block):
//   hv = leaky_relu( sum_e support[src_s]*w_s + b1 );  support2 = hv @ W2.
// Sorted payloads kill the edge_idx indirection; 64 edges' src/w loaded
// lane-parallel then shfl-broadcast; gathers issued 4-deep independent.
// W2 rows live in 24 registers per lane (no LDS).
// ---------------------------------------------------------------------------
__global__ __launch_bounds__(256) void agg1_fused_kernel(
    const float* __restrict__ support, const int* __restrict__ row_ptr,
    const int* __restrict__ src_s, const float* __restrict__ w_s,
    const float* __restrict__ b1, const float* __restrict__ W2,
    float* __restrict__ support2)
{
    const int t    = threadIdx.x;
    const int node = blockIdx.x * 4 + (t >> 6);
    const int lane = t & 63;
    if (node >= N_NODES) return;

    float w2f[24];                 // W2[(lane*4+c)*6 + j] -> w2f[c*6+j]
    {
        const float4* wp = (const float4*)(W2 + lane * 24);
#pragma unroll
        for (int q = 0; q < 6; ++q) ((float4*)w2f)[q] = wp[q];
    }

    const int p0 = row_ptr[node], p1 = row_ptr[node + 1];
    float4 acc = make_float4(0.f, 0.f, 0.f, 0.f);
    for (int base = p0; base < p1; base += 64) {
        const int rem = p1 - base;
        const int n = rem < 64 ? rem : 64;
        int se = 0; float we = 0.f;
        if (lane < n) { se = src_s[base + lane]; we = w_s[base + lane]; }
        int i = 0;
        for (; i + 4 <= n; i += 4) {
            const int   s0 = __shfl(se, i),     s1 = __shfl(se, i + 1);
            const int   s2 = __shfl(se, i + 2), s3 = __shfl(se, i + 3);
            const float q0 = __shfl(we, i),     q1 = __shfl(we, i + 1);
            const float q2 = __shfl(we, i + 2), q3 = __shfl(we, i + 3);
            const float4 v0 = *(const float4*)&support[(size_t)s0 * NUM_DIM + lane * 4];
            const float4 v1 = *(const float4*)&support[(size_t)s1 * NUM_DIM + lane * 4];
            const float4 v2 = *(const float4*)&support[(size_t)s2 * NUM_DIM + lane * 4];
            const float4 v3 = *(const float4*)&support[(size_t)s3 * NUM_DIM + lane * 4];
            acc.x += v0.x * q0 + v1.x * q1 + v2.x * q2 + v3.x * q3;
            acc.y += v0.y * q0 + v1.y * q1 + v2.y * q2 + v3.y * q3;
            acc.z += v0.z * q0 + v1.z * q1 + v2.z * q2 + v3.z * q3;
            acc.w += v0.w * q0 + v1.w * q1 + v2.w * q2 + v3.w * q3;
        }
        for (; i < n; ++i) {
            const int   s0 = __shfl(se, i);
            const float q0 = __shfl(we, i);
            const float4 v = *(const float4*)&support[(size_t)s0 * NUM_DIM + lane * 4];
            acc.x += v.x * q0; acc.y += v.y * q0;
            acc.z += v.z * q0; acc.w += v.w * q0;
        }
    }

    const float4 bv = *(const float4*)&b1[lane * 4];
    float hv[4] = {acc.x + bv.x, acc.y + bv.y, acc.z + bv.z, acc.w + bv.w};
#pragma unroll
    for (int c = 0; c < 4; ++c) hv[c] = (hv[c] > 0.f) ? hv[c] : 0.01f * hv[c];

    float o[NUM_OUT];
#pragma unroll
    for (int j = 0; j < NUM_OUT; ++j)
        o[j] = hv[0] * w2f[j] + hv[1] * w2f[6 + j] +
               hv[2] * w2f[12 + j] + hv[3] * w2f[18 + j];
#pragma unroll
    for (int j = 0; j < NUM_OUT; ++j) {
#pragma unroll
        for (int off = 32; off > 0; off >>= 1)
            o[j] += __shfl_down(o[j], off);
    }
    if (lane == 0) {
#pragma unroll
        for (int j = 0; j < NUM_OUT; ++j)
            support2[(size_t)node * NUM_OUT + j] = o[j];
    }
}

// ---------------------------------------------------------------------------
// agg2_fused: per dst node (one wave): v = sum_e support2[src_s]*w_s + b2;
// out = log_softmax(v). support2 is 1.2MB -> L2-resident.
// ---------------------------------------------------------------------------
__global__ __launch_bounds__(256) void agg2_fused_kernel(
    const float* __restrict__ support2, const int* __restrict__ row_ptr,
    const int* __restrict__ src_s, const float* __restrict__ w_s,
    const float* __restrict__ b2, float* __restrict__ out)
{
    const int t    = threadIdx.x;
    const int node = blockIdx.x * 4 + (t >> 6);
    const int lane = t & 63;
    if (node >= N_NODES) return;

    const int p0 = row_ptr[node], p1 = row_ptr[node + 1];
    float o[NUM_OUT] = {0.f, 0.f, 0.f, 0.f, 0.f, 0.f};
    for (int p = p0 + lane; p < p1; p += 64) {
        const int   s  = src_s[p];
        const float ww = w_s[p];
        const float2* sp = (const float2*)(support2 + (size_t)s * NUM_OUT);
        const float2 v0 = sp[0], v1 = sp[1], v2 = sp[2];
        o[0] += v0.x * ww; o[1] += v0.y * ww;
        o[2] += v1.x * ww; o[3] += v1.y * ww;
        o[4] += v2.x * ww; o[5] += v2.y * ww;
    }
#pragma unroll
    for (int j = 0; j < NUM_OUT; ++j) {
#pragma unroll
        for (int off = 32; off > 0; off >>= 1)
            o[j] += __shfl_down(o[j], off);
    }
    if (lane == 0) {
        float v[NUM_OUT];
        float m = -1e30f;
#pragma unroll
        for (int j = 0; j < NUM_OUT; ++j) {
            v[j] = o[j] + b2[j];
            m = fmaxf(m, v[j]);
        }
        float s = 0.f;
#pragma unroll
        for (int j = 0; j < NUM_OUT; ++j) s += expf(v[j] - m);
        const float ls = logf(s);
#pragma unroll
        for (int j = 0; j < NUM_OUT; ++j)
            out[(size_t)node * NUM_OUT + j] = v[j] - m - ls;
    }
}

extern "C" void kernel_launch(void* const* d_in, const int* in_sizes, int n_in,
                              void* d_out, int out_size, void* d_ws, size_t ws_size,
                              hipStream_t stream)
{
    const float* x   = (const float*)d_in[0];
    const int*   src = (const int*)  d_in[1];
    const int*   dst = (const int*)  d_in[2];
    const float* w   = (const float*)d_in[3];
    const float* W1  = (const float*)d_in[4];
    const float* b1  = (const float*)d_in[5];
    const float* W2  = (const float*)d_in[6];
    const float* b2  = (const float*)d_in[7];
    float* out = (float*)d_out;

    // Workspace layout (bytes):
    //   support1: [0,          51,200,000)   50000*256 f32
    //   support2: [51,200,000, 52,400,000)   50000*6  f32
    //   Wimg:     [52,400,000, 56,201,088)   116 tiles * 32 KB bf16 (pre-swizzled)
    //   deg/cur:  [56,201,088, 56,401,088)   50000 i32
    //   row_ptr:  [56,401,088, 56,601,092)   50001 i32
    //   src_s:    [56,601,092, 58,201,092)   400000 i32 (CSR-sorted)
    //   w_s:      [58,201,092, 59,801,092)   400000 f32 (CSR-sorted)
    char* ws = (char*)d_ws;
    float*          support1 = (float*)(ws);
    float*          support2 = (float*)(ws + 51200000);
    unsigned short* Wimg     = (unsigned short*)(ws + 52400000);
    int*            deg_cur  = (int*)(ws + 56201088);
    int*            row_ptr  = (int*)(ws + 56401088);
    int*            src_s    = (int*)(ws + 56601092);
    float*          w_s      = (float*)(ws + 58201092);

    hipMemsetAsync(deg_cur, 0, (size_t)N_NODES * sizeof(int), stream);

    deg_count_kernel<<<dim3((N_EDGES + 255) / 256), 256, 0, stream>>>(dst, deg_cur);
    scan_kernel<<<dim3(1), 1024, 0, stream>>>(deg_cur, row_ptr, deg_cur);
    fill_kernel<<<dim3((N_EDGES + 255) / 256), 256, 0, stream>>>(
        dst, src, w, deg_cur, src_s, w_s);

    w1_img_kernel<<<dim3((KTILES * 1024 + 255) / 256), 256, 0, stream>>>(W1, Wimg);
    gemm1_kernel<<<dim3((N_NODES + 63) / 64), 256, 0, stream>>>(x, Wimg, support1);
    agg1_fused_kernel<<<dim3((N_NODES + 3) / 4), 256, 0, stream>>>(
        support1, row_ptr, src_s, w_s, b1, W2, support2);
    agg2_fused_kernel<<<dim3((N_NODES + 3) / 4), 256, 0, stream>>>(
        support2, row_ptr, src_s, w_s, b2, out);
}